// Round 1
// baseline (28.710 us; speedup 1.0000x reference)
//
#include <hip/hip_runtime.h>
#include <math.h>

#define N_NODES 100000
#define D_FEAT  128
#define N_EDGES 640000

// ---------------------------------------------------------------------------
// Kernel 1: per-node dot products with W[:128] (-> a) and W[128:] (-> c).
// One 64-lane wave per node; each lane loads float2 (8 B) => 512 B contiguous
// per row per wave (fully coalesced). Wave shuffle-reduce, lane 0 stores.
// ---------------------------------------------------------------------------
__global__ void node_dots_kernel(const float* __restrict__ feat,
                                 const float* __restrict__ W,
                                 float* __restrict__ a,
                                 float* __restrict__ c)
{
    const int lane = threadIdx.x & 63;
    const int wave_in_block = threadIdx.x >> 6;
    const int node = blockIdx.x * (blockDim.x >> 6) + wave_in_block;
    if (node >= N_NODES) return;

    const float2 f  = *reinterpret_cast<const float2*>(feat + (size_t)node * D_FEAT + lane * 2);
    const float2 w0 = *reinterpret_cast<const float2*>(W + lane * 2);
    const float2 w1 = *reinterpret_cast<const float2*>(W + D_FEAT + lane * 2);

    float pa = f.x * w0.x + f.y * w0.y;
    float pc = f.x * w1.x + f.y * w1.y;

    // wave-64 butterfly-free tree reduce
    #pragma unroll
    for (int off = 32; off > 0; off >>= 1) {
        pa += __shfl_down(pa, off, 64);
        pc += __shfl_down(pc, off, 64);
    }
    if (lane == 0) {
        a[node] = pa;
        c[node] = pc;
    }
}

// ---------------------------------------------------------------------------
// Kernel 2: per-edge gather of precomputed dots + sigmoid.
// Gather tables are 400 KB each -> L2-resident on every XCD.
// ---------------------------------------------------------------------------
__global__ void edge_kernel(const int* __restrict__ ei,
                            const float* __restrict__ a,
                            const float* __restrict__ c,
                            const float* __restrict__ b,
                            float* __restrict__ out)
{
    const int e = blockIdx.x * blockDim.x + threadIdx.x;
    if (e >= N_EDGES) return;
    const int s = ei[e];
    const int d = ei[N_EDGES + e];
    const float logit = a[s] + c[d] + b[0];
    out[e] = 1.0f / (1.0f + __expf(-logit));
}

// ---------------------------------------------------------------------------
// Fallback (only if ws_size is too small): fused wave-per-edge direct dot.
// ---------------------------------------------------------------------------
__global__ void edge_fused_kernel(const float* __restrict__ feat,
                                  const int* __restrict__ ei,
                                  const float* __restrict__ W,
                                  const float* __restrict__ b,
                                  float* __restrict__ out)
{
    const int gid  = blockIdx.x * blockDim.x + threadIdx.x;
    const int wid  = gid >> 6;
    const int lane = gid & 63;
    if (wid >= N_EDGES) return;

    const int s = ei[wid];
    const int d = ei[N_EDGES + wid];

    const float2 fs = *reinterpret_cast<const float2*>(feat + (size_t)s * D_FEAT + lane * 2);
    const float2 fd = *reinterpret_cast<const float2*>(feat + (size_t)d * D_FEAT + lane * 2);
    const float2 w0 = *reinterpret_cast<const float2*>(W + lane * 2);
    const float2 w1 = *reinterpret_cast<const float2*>(W + D_FEAT + lane * 2);

    float p = fs.x * w0.x + fs.y * w0.y + fd.x * w1.x + fd.y * w1.y;
    #pragma unroll
    for (int off = 32; off > 0; off >>= 1) p += __shfl_down(p, off, 64);

    if (lane == 0) out[wid] = 1.0f / (1.0f + __expf(-(p + b[0])));
}

extern "C" void kernel_launch(void* const* d_in, const int* in_sizes, int n_in,
                              void* d_out, int out_size, void* d_ws, size_t ws_size,
                              hipStream_t stream)
{
    const float* feat = (const float*)d_in[0];
    const int*   ei   = (const int*)d_in[1];   // harness contract: integer -> const int*
    const float* W    = (const float*)d_in[2];
    const float* b    = (const float*)d_in[3];
    float*       out  = (float*)d_out;

    const size_t ws_needed = 2ull * N_NODES * sizeof(float);

    if (ws_size >= ws_needed) {
        float* a = (float*)d_ws;
        float* c = a + N_NODES;

        // Kernel 1: 4 waves/block -> 4 nodes/block
        const int waves_per_block = 256 / 64;
        const int nblk1 = (N_NODES + waves_per_block - 1) / waves_per_block;
        node_dots_kernel<<<nblk1, 256, 0, stream>>>(feat, W, a, c);

        // Kernel 2: one thread per edge
        const int nblk2 = (N_EDGES + 255) / 256;
        edge_kernel<<<nblk2, 256, 0, stream>>>(ei, a, c, b, out);
    } else {
        // Fallback: wave per edge, direct dot products
        const long long total_threads = (long long)N_EDGES * 64;
        const int nblk = (int)((total_threads + 255) / 256);
        edge_fused_kernel<<<nblk, 256, 0, stream>>>(feat, ei, W, b, out);
    }
}

// Round 2
// 22.519 us; speedup vs baseline: 1.2749x; 1.2749x over previous
//
#include <hip/hip_runtime.h>
#include <math.h>

#define N_NODES 100000
#define D_FEAT  128
#define N_EDGES 640000

// ---------------------------------------------------------------------------
// Kernel 1: per-node dot products with W[:128] (-> a) and W[128:] (-> c).
// 32-lane row-groups; each lane loads float4 (16 B) => one full 512 B row per
// group per load. Each group processes 2 nodes per iteration with both row
// loads issued before either reduction (2 loads in flight). Grid-stride.
// ---------------------------------------------------------------------------
__global__ void node_dots_kernel(const float* __restrict__ feat,
                                 const float* __restrict__ W,
                                 float* __restrict__ a,
                                 float* __restrict__ c)
{
    const int lane32 = threadIdx.x & 31;
    const int grp    = (blockIdx.x * blockDim.x + threadIdx.x) >> 5;
    const int ngrp   = (gridDim.x * blockDim.x) >> 5;

    // W fragments held in registers across the whole loop
    const float4 w0 = *reinterpret_cast<const float4*>(W + lane32 * 4);
    const float4 w1 = *reinterpret_cast<const float4*>(W + D_FEAT + lane32 * 4);

    for (int n0 = grp * 2; n0 < N_NODES; n0 += ngrp * 2) {
        const int n1 = n0 + 1;
        const bool has1 = (n1 < N_NODES);

        // Issue both row loads before any reduction work
        const float4 f0 = *reinterpret_cast<const float4*>(feat + (size_t)n0 * D_FEAT + lane32 * 4);
        const float4 f1 = has1
            ? *reinterpret_cast<const float4*>(feat + (size_t)n1 * D_FEAT + lane32 * 4)
            : make_float4(0.f, 0.f, 0.f, 0.f);

        float pa0 = f0.x * w0.x + f0.y * w0.y + f0.z * w0.z + f0.w * w0.w;
        float pc0 = f0.x * w1.x + f0.y * w1.y + f0.z * w1.z + f0.w * w1.w;
        float pa1 = f1.x * w0.x + f1.y * w0.y + f1.z * w0.z + f1.w * w0.w;
        float pc1 = f1.x * w1.x + f1.y * w1.y + f1.z * w1.z + f1.w * w1.w;

        #pragma unroll
        for (int off = 16; off > 0; off >>= 1) {
            pa0 += __shfl_down(pa0, off, 32);
            pc0 += __shfl_down(pc0, off, 32);
            pa1 += __shfl_down(pa1, off, 32);
            pc1 += __shfl_down(pc1, off, 32);
        }
        if (lane32 == 0) {
            a[n0] = pa0;
            c[n0] = pc0;
            if (has1) {
                a[n1] = pa1;
                c[n1] = pc1;
            }
        }
    }
}

// ---------------------------------------------------------------------------
// Kernel 2: per-edge gather of precomputed dots + sigmoid, 4 edges/thread.
// Gather tables are 400 KB each -> L2-resident on every XCD.
// ---------------------------------------------------------------------------
__global__ void edge_kernel(const int* __restrict__ ei,
                            const float* __restrict__ a,
                            const float* __restrict__ c,
                            const float* __restrict__ b,
                            float* __restrict__ out)
{
    const int t = blockIdx.x * blockDim.x + threadIdx.x;
    const int e0 = t * 4;
    if (e0 >= N_EDGES) return;

    const float bb = b[0];
    const int4 s = *reinterpret_cast<const int4*>(ei + e0);
    const int4 d = *reinterpret_cast<const int4*>(ei + N_EDGES + e0);

    float4 o;
    o.x = 1.0f / (1.0f + __expf(-(a[s.x] + c[d.x] + bb)));
    o.y = 1.0f / (1.0f + __expf(-(a[s.y] + c[d.y] + bb)));
    o.z = 1.0f / (1.0f + __expf(-(a[s.z] + c[d.z] + bb)));
    o.w = 1.0f / (1.0f + __expf(-(a[s.w] + c[d.w] + bb)));

    *reinterpret_cast<float4*>(out + e0) = o;
}

// ---------------------------------------------------------------------------
// Fallback (only if ws_size is too small): fused wave-per-edge direct dot.
// ---------------------------------------------------------------------------
__global__ void edge_fused_kernel(const float* __restrict__ feat,
                                  const int* __restrict__ ei,
                                  const float* __restrict__ W,
                                  const float* __restrict__ b,
                                  float* __restrict__ out)
{
    const int gid  = blockIdx.x * blockDim.x + threadIdx.x;
    const int wid  = gid >> 6;
    const int lane = gid & 63;
    if (wid >= N_EDGES) return;

    const int s = ei[wid];
    const int d = ei[N_EDGES + wid];

    const float2 fs = *reinterpret_cast<const float2*>(feat + (size_t)s * D_FEAT + lane * 2);
    const float2 fd = *reinterpret_cast<const float2*>(feat + (size_t)d * D_FEAT + lane * 2);
    const float2 w0 = *reinterpret_cast<const float2*>(W + lane * 2);
    const float2 w1 = *reinterpret_cast<const float2*>(W + D_FEAT + lane * 2);

    float p = fs.x * w0.x + fs.y * w0.y + fd.x * w1.x + fd.y * w1.y;
    #pragma unroll
    for (int off = 32; off > 0; off >>= 1) p += __shfl_down(p, off, 64);

    if (lane == 0) out[wid] = 1.0f / (1.0f + __expf(-(p + b[0])));
}

extern "C" void kernel_launch(void* const* d_in, const int* in_sizes, int n_in,
                              void* d_out, int out_size, void* d_ws, size_t ws_size,
                              hipStream_t stream)
{
    const float* feat = (const float*)d_in[0];
    const int*   ei   = (const int*)d_in[1];   // harness converts int64 -> int32
    const float* W    = (const float*)d_in[2];
    const float* b    = (const float*)d_in[3];
    float*       out  = (float*)d_out;

    const size_t ws_needed = 2ull * N_NODES * sizeof(float);

    if (ws_size >= ws_needed) {
        float* a = (float*)d_ws;
        float* c = a + N_NODES;

        // Kernel 1: 1024 blocks x 8 groups x 2 nodes = 16384 nodes per sweep,
        // ~6 grid-stride iterations per group.
        node_dots_kernel<<<1024, 256, 0, stream>>>(feat, W, a, c);

        // Kernel 2: 4 edges per thread
        const int nthreads = N_EDGES / 4;               // 160000
        const int nblk2 = (nthreads + 255) / 256;       // 625
        edge_kernel<<<nblk2, 256, 0, stream>>>(ei, a, c, b, out);
    } else {
        // Fallback: wave per edge, direct dot products
        const long long total_threads = (long long)N_EDGES * 64;
        const int nblk = (int)((total_threads + 255) / 256);
        edge_fused_kernel<<<nblk, 256, 0, stream>>>(feat, ei, W, b, out);
    }
}